// Round 6
// baseline (207.761 us; speedup 1.0000x reference)
//
#include <hip/hip_runtime.h>
#include <hip/hip_bf16.h>
#include <math.h>

typedef __bf16 bf16;
typedef __bf16 bf16x4 __attribute__((ext_vector_type(4)));
typedef __bf16 bf16x8 __attribute__((ext_vector_type(8)));
typedef float  f32x4  __attribute__((ext_vector_type(4)));

#define MM 2048   // seq len
#define DD 1024   // model dim
#define HD 64     // head dim

// async global->LDS, 16B per lane. LDS dest must be wave-uniform base + lane*16.
__device__ __forceinline__ void gload16(const void* g, void* l) {
  __builtin_amdgcn_global_load_lds((const __attribute__((address_space(1))) void*)g,
                                   (__attribute__((address_space(3))) void*)l, 16, 0, 0);
}

// ---------------- fp32 -> bf16 conversion (all tensors, one launch) -------
__global__ __launch_bounds__(256) void k_cvt_all(
    const float* __restrict__ x,   const float* __restrict__ wq,
    const float* __restrict__ wk,  const float* __restrict__ wv,
    const float* __restrict__ ipw, const float* __restrict__ ow,
    bf16* __restrict__ xb,  bf16* __restrict__ wqb, bf16* __restrict__ wkb,
    bf16* __restrict__ wvb, bf16* __restrict__ ipwb, bf16* __restrict__ owb)
{
  int bid = blockIdx.x;
  const float* s; bf16* d; int base;
  if (bid < 4096)       { s = x;   d = xb;   base = bid; }
  else if (bid < 5120)  { s = wq;  d = wqb;  base = bid - 4096; }
  else if (bid < 6144)  { s = wk;  d = wkb;  base = bid - 5120; }
  else if (bid < 7168)  { s = wv;  d = wvb;  base = bid - 6144; }
  else if (bid < 10240) { s = ipw; d = ipwb; base = bid - 7168; }
  else                  { s = ow;  d = owb;  base = bid - 10240; }
  int i = base*256 + threadIdx.x;          // float4 index
  float4 v = ((const float4*)s)[i];
  bf16x4 o;
  o[0]=(bf16)v.x; o[1]=(bf16)v.y; o[2]=(bf16)v.z; o[3]=(bf16)v.w;
  ((bf16x4*)d)[i] = o;
}

// ============ 256x256 big-tile GEMM core: C = A(256xK) * B(256xK)^T =======
// 512 threads = 8 waves (2 row x 4 col), wave does 128x64 (8x4 16x16x32).
// 4 LDS buffers x (A 16KB + B 16KB), depth-3 prefetch via global_load_lds,
// counted vmcnt(8) (tail 4,0), ONE barrier per K-tile (BK=32, K=1024 -> 32).
// LDS layout per tile: [256 rows][4 chunks of 16B], physical chunk
// p = (logical + ((row>>1)&3)) & 3  -- rotation, conflict-free ds_read_b128
// (measured 0 conflicts, r4). Rotation folded into per-lane GLOBAL source.
__device__ __forceinline__ void gemm_core256(const bf16* __restrict__ A,
                                             const bf16* __restrict__ Bw,
                                             const int row0, const int col0,
                                             bf16* __restrict__ sA, bf16* __restrict__ sB,
                                             f32x4 (&acc)[8][4])
{
  const int t = threadIdx.x;
  #pragma unroll
  for (int m=0;m<8;m++)
    #pragma unroll
    for (int n=0;n<4;n++)
      acc[m][n] = (f32x4){0.f,0.f,0.f,0.f};

  // staging: slot t -> (row = t>>2, phys chunk p = t&3); logical chunk
  // l = (p - ((row>>1)&3)) & 3.  Second slot = same +128 rows (same l).
  const int csw = ((t & 3) - ((t >> 3) & 3)) & 3;
  const bf16* gA = A  + (size_t)(row0 + (t>>2))*DD + csw*8;
  const bf16* gB = Bw + (size_t)(col0 + (t>>2))*DD + csw*8;
  char* lA = (char*)sA + t*16;
  char* lB = (char*)sB + t*16;

  const int lane = t & 63;
  const int wid  = t >> 6;
  const int wr = wid >> 2, wc = wid & 3;     // 2 x 4 wave grid
  const int fr = lane & 15, fg = lane >> 4;
  // fragment read: row R, logical chunk fg -> phys ((fg + ((fr>>1)&3))&3)
  const int chS = ((fg + ((fr >> 1) & 3)) & 3) * 16;
  const int fA = (wr*128 + fr)*64 + chS;     // + m*1024
  const int fB = (wc*64  + fr)*64 + chS;     // + n*1024

  // prologue: stage tiles 0,1,2
  #pragma unroll
  for (int p=0;p<3;p++) {
    gload16(gA + p*32,            lA + p*16384);
    gload16(gA + (size_t)128*DD + p*32, lA + p*16384 + 8192);
    gload16(gB + p*32,            lB + p*16384);
    gload16(gB + (size_t)128*DD + p*32, lB + p*16384 + 8192);
  }

  for (int kt = 0; kt < 32; ++kt) {
    if (kt < 30)       asm volatile("s_waitcnt vmcnt(8)" ::: "memory");
    else if (kt == 30) asm volatile("s_waitcnt vmcnt(4)" ::: "memory");
    else               asm volatile("s_waitcnt vmcnt(0)" ::: "memory");
    __builtin_amdgcn_s_barrier();          // tile kt ready; buf (kt+3)&3 free
    if (kt < 29) {                          // prefetch tile kt+3
      const int Ts = kt + 3;
      const int nb = Ts & 3;
      gload16(gA + Ts*32,            lA + nb*16384);
      gload16(gA + (size_t)128*DD + Ts*32, lA + nb*16384 + 8192);
      gload16(gB + Ts*32,            lB + nb*16384);
      gload16(gB + (size_t)128*DD + Ts*32, lB + nb*16384 + 8192);
    }
    const char* bA = (const char*)sA + (kt&3)*16384;
    const char* bB = (const char*)sB + (kt&3)*16384;
    bf16x8 bF[4], aF[4];
    #pragma unroll
    for (int n=0;n<4;n++) bF[n] = *(const bf16x8*)(bB + fB + n*1024);
    #pragma unroll
    for (int m=0;m<4;m++) aF[m] = *(const bf16x8*)(bA + fA + m*1024);
    __builtin_amdgcn_s_setprio(1);
    #pragma unroll
    for (int m=0;m<4;m++)
      #pragma unroll
      for (int n=0;n<4;n++)
        acc[m][n] = __builtin_amdgcn_mfma_f32_16x16x32_bf16(aF[m], bF[n], acc[m][n], 0, 0, 0);
    __builtin_amdgcn_s_setprio(0);
    #pragma unroll
    for (int m=0;m<4;m++) aF[m] = *(const bf16x8*)(bA + fA + (m+4)*1024);
    __builtin_amdgcn_s_setprio(1);
    #pragma unroll
    for (int m=0;m<4;m++)
      #pragma unroll
      for (int n=0;n<4;n++)
        acc[m+4][n] = __builtin_amdgcn_mfma_f32_16x16x32_bf16(aF[m], bF[n], acc[m+4][n], 0, 0, 0);
    __builtin_amdgcn_s_setprio(0);
  }
}

// ---------------- GEMM 1 (256q): q/k/v = rope(x @ W^T) --------------------
__global__ __launch_bounds__(512, 2) void k_rope256(
    const bf16* __restrict__ X, const bf16* __restrict__ Wq,
    const bf16* __restrict__ Wk, const bf16* __restrict__ Wv,
    bf16* __restrict__ QKV)
{
  __shared__ bf16 sA[4*256*32];   // 64 KB
  __shared__ bf16 sB[4*256*32];   // 64 KB
  const int row0 = blockIdx.x * 256;
  const int col0 = blockIdx.y * 256;
  const int z = blockIdx.z;
  const bf16* Bw = (z==0) ? Wq : ((z==1) ? Wk : Wv);
  f32x4 acc[8][4];
  gemm_core256(X, Bw, row0, col0, sA, sB, acc);

  bf16* outp = QKV + (size_t)z * (4096u*1024u);
  const int lane = threadIdx.x & 63, wid = threadIdx.x >> 6;
  const int wr = wid >> 2, wc = wid & 3;
  const int fr = lane & 15, fg = lane >> 4;
  #pragma unroll
  for (int n=0;n<4;n++) {
    const int gc = col0 + wc*64 + n*16 + fr;
    const int i2 = gc >> 1;
    const float theta = __expf(((float)i2 - 1.0f) * (-2.0f * 9.210340371976184f / 1024.0f));
    #pragma unroll
    for (int m=0;m<8;m++) {
      #pragma unroll
      for (int r=0;r<4;r++) {
        const int gr = row0 + wr*128 + m*16 + fg*4 + r;
        const float v  = acc[m][n][r];
        const float pv = __shfl_xor(v, 1);      // partner column of the pair
        const int pos = gr & (MM-1);
        float sv, cv;
        __sincosf((float)pos * theta, &sv, &cv);
        const float res = (gc & 1) ? (v*cv - pv*sv) : (v*cv + pv*sv);
        outp[(size_t)gr * DD + gc] = (bf16)res;
      }
    }
  }
}

// --------- GEMM 2 (256q): qh/kh = q/k @ Wi^T + b, vh TRANSPOSED -----------
__global__ __launch_bounds__(512, 2) void k_proj256(
    const bf16* __restrict__ QKV, const bf16* __restrict__ IPW,
    const float* __restrict__ IPB,
    bf16* __restrict__ QH, bf16* __restrict__ KH, bf16* __restrict__ VT)
{
  __shared__ bf16 sA[4*256*32];
  __shared__ bf16 sB[4*256*32];
  const int row0 = blockIdx.x * 256;
  const int col0 = blockIdx.y * 256;
  const int z = blockIdx.z;
  const bf16* A  = QKV + (size_t)z * (4096u*1024u);
  const bf16* Bw = IPW + (size_t)z * (1024u*1024u);
  const float* bias = IPB + z * DD;
  f32x4 acc[8][4];
  gemm_core256(A, Bw, row0, col0, sA, sB, acc);

  const int lane = threadIdx.x & 63, wid = threadIdx.x >> 6;
  const int wr = wid >> 2, wc = wid & 3;
  const int fr = lane & 15, fg = lane >> 4;
  if (z < 2) {
    bf16* outp = (z==0) ? QH : KH;
    #pragma unroll
    for (int n=0;n<4;n++) {
      const int gc = col0 + wc*64 + n*16 + fr;
      const float bs = bias[gc];
      #pragma unroll
      for (int m=0;m<8;m++) {
        #pragma unroll
        for (int r=0;r<4;r++) {
          const int gr = row0 + wr*128 + m*16 + fg*4 + r;
          outp[(size_t)gr * DD + gc] = (bf16)(acc[m][n][r] + bs);
        }
      }
    }
  } else {
    // VT layout: (B, D, M) so attention PV B-frags read contiguous along m
    #pragma unroll
    for (int n=0;n<4;n++) {
      const int gc = col0 + wc*64 + n*16 + fr;
      const float bs = bias[gc];
      #pragma unroll
      for (int m=0;m<8;m++) {
        const int gr0 = row0 + wr*128 + m*16 + fg*4;   // 4 consecutive rows
        const int b  = gr0 >> 11;
        const int m0 = gr0 & (MM-1);
        bf16x4 pk;
        #pragma unroll
        for (int r=0;r<4;r++) pk[r] = (bf16)(acc[m][n][r] + bs);
        *(bf16x4*)(VT + ((size_t)b*DD + gc)*MM + m0) = pk;
      }
    }
  }
}

// ---------------- 128-tile GEMM core (kept for the output GEMM) -----------
__device__ __forceinline__ void gemm_core128(const bf16* __restrict__ A,
                                             const bf16* __restrict__ Bw,
                                             const int row0, const int col0,
                                             bf16* __restrict__ sA, bf16* __restrict__ sB,
                                             f32x4 (&acc)[4][4])
{
  const int t = threadIdx.x;
  #pragma unroll
  for (int m=0;m<4;m++)
    #pragma unroll
    for (int n=0;n<4;n++)
      acc[m][n] = (f32x4){0.f,0.f,0.f,0.f};

  const int csw = ((t & 3) - ((t >> 3) & 3)) & 3;
  const bf16* gA0 = A  + (size_t)(row0 + (t>>2))*DD + csw*8;
  const bf16* gA1 = gA0 + (size_t)64*DD;
  const bf16* gB0 = Bw + (size_t)(col0 + (t>>2))*DD + csw*8;
  const bf16* gB1 = gB0 + (size_t)64*DD;
  char* lA = (char*)sA + t*16;
  char* lB = (char*)sB + t*16;

  const int lane = t & 63;
  const int wid  = t >> 6;
  const int wr = wid >> 1, wc = wid & 1;
  const int fr = lane & 15, fg = lane >> 4;
  const int chS = ((fg + ((fr >> 1) & 3)) & 3) * 16;
  const int fA = (wr*64 + fr)*64 + chS;
  const int fB = (wc*64 + fr)*64 + chS;

  gload16(gA0, lA);        gload16(gA1, lA + 4096);
  gload16(gB0, lB);        gload16(gB1, lB + 4096);
  gload16(gA0 + 32, lA + 8192);   gload16(gA1 + 32, lA + 8192 + 4096);
  gload16(gB0 + 32, lB + 8192);   gload16(gB1 + 32, lB + 8192 + 4096);

  int c = 0;
  for (int kt = 0; kt < 32; ++kt) {
    if (kt < 31) asm volatile("s_waitcnt vmcnt(4)" ::: "memory");
    else         asm volatile("s_waitcnt vmcnt(0)" ::: "memory");
    __builtin_amdgcn_s_barrier();
    if (kt < 30) {
      const int nb = (c + 2 < 3) ? c + 2 : c - 1;
      const int ko = (kt + 2) * 32;
      gload16(gA0 + ko, lA + nb*8192);   gload16(gA1 + ko, lA + nb*8192 + 4096);
      gload16(gB0 + ko, lB + nb*8192);   gload16(gB1 + ko, lB + nb*8192 + 4096);
    }
    const char* qA = (const char*)sA + c*8192 + fA;
    const char* qB = (const char*)sB + c*8192 + fB;
    bf16x8 aF[4], bF[4];
    #pragma unroll
    for (int m=0;m<4;m++) aF[m] = *(const bf16x8*)(qA + m*1024);
    #pragma unroll
    for (int n=0;n<4;n++) bF[n] = *(const bf16x8*)(qB + n*1024);
    __builtin_amdgcn_s_setprio(1);
    #pragma unroll
    for (int m=0;m<4;m++)
      #pragma unroll
      for (int n=0;n<4;n++)
        acc[m][n] = __builtin_amdgcn_mfma_f32_16x16x32_bf16(aF[m], bF[n], acc[m][n], 0, 0, 0);
    __builtin_amdgcn_s_setprio(0);
    c = (c == 2) ? 0 : c + 1;
  }
}

// ---------------- flash attention (causal) --------------------------------
// 1024 blocks (one 64-row q-tile each, LPT order), 2-buffer K/V pipeline
// (global_load_lds, pre-swizzled source), 1 barrier + drain-own vmcnt per
// tile, 40KB LDS -> 4 blocks/CU. Swapped QK^T: softmax is lane-local.
__global__ __launch_bounds__(256) void k_attn(
    const bf16* __restrict__ QH, const bf16* __restrict__ KH,
    const bf16* __restrict__ VT, bf16* __restrict__ O)
{
  __shared__ bf16 sK[2*64*64];    // [buf][kv][d] rows of 128B, swizzled
  __shared__ bf16 sV[2*64*64];    // [buf][d][kv] (from VT), swizzled
  __shared__ bf16 sP[4*16*64];    // per-wave P tile [16 q][64 kv] swizzled
  const int qt = 31 - (int)blockIdx.x;       // longest first
  const int h = blockIdx.y, b = blockIdx.z;
  const int t = threadIdx.x, lane = t & 63, wid = t >> 6;
  const int fr = lane & 15, fg = lane >> 4;
  const int swzP = (fr & 7) << 4;
  const int q0 = qt * 64;
  const int qg = q0 + wid*16 + fr;           // this lane's q row (softmax)

  // staging geometry (pre-swizzled global source, linear LDS dest t*16)
  const int srow = t >> 3;                       // 0..31
  const int cc   = (t & 7) ^ (srow & 7);
  const bf16* gK0 = KH + ((size_t)b*MM + srow)*DD + h*HD + cc*8;
  const bf16* gK1 = gK0 + (size_t)32*DD;
  const bf16* gV0 = VT + ((size_t)b*DD + h*HD + srow)*MM + cc*8;
  const bf16* gV1 = gV0 + (size_t)32*MM;
  char* lK = (char*)sK + t*16;
  char* lV = (char*)sV + t*16;
  char* sPw = (char*)(sP + wid*16*64);

  const bf16* qp = QH + ((size_t)b*MM + qg)*DD + h*HD + fg*8;
  bf16x8 aQ0 = *(const bf16x8*)qp;
  bf16x8 aQ1 = *(const bf16x8*)(qp + 32);

  // stage tile 0 into buffer 0
  gload16(gK0, lK);  gload16(gK1, lK + 4096);
  gload16(gV0, lV);  gload16(gV1, lV + 4096);

  f32x4 o_acc[4];
  #pragma unroll
  for (int n=0;n<4;n++) o_acc[n] = (f32x4){0.f,0.f,0.f,0.f};
  float mrow = -INFINITY, lrow = 0.f;

  for (int kt = 0; kt <= qt; ++kt) {
    const int c = kt & 1;
    asm volatile("s_waitcnt vmcnt(0)" ::: "memory");   // own tile-kt DMA done
    __builtin_amdgcn_s_barrier();                      // all waves' done; buf c^1 free
    if (kt < qt) {                                     // stage next tile
      const int nb = c ^ 1;
      gload16(gK0 + (size_t)(kt+1)*64*DD, lK + nb*8192);
      gload16(gK1 + (size_t)(kt+1)*64*DD, lK + nb*8192 + 4096);
      gload16(gV0 + (kt+1)*64,            lV + nb*8192);
      gload16(gV1 + (kt+1)*64,            lV + nb*8192 + 4096);
    }
    const char* bKb = (const char*)sK + c*8192;
    const char* bVb = (const char*)sV + c*8192;

    // S^T = K Q^T : lane holds S[kv=n*16+fg*4+r][q=fr]
    f32x4 sacc[4];
    #pragma unroll
    for (int n=0;n<4;n++) sacc[n] = (f32x4){0.f,0.f,0.f,0.f};
    __builtin_amdgcn_s_setprio(1);
    #pragma unroll
    for (int kb=0;kb<2;kb++) {
      const bf16x8 q = kb ? aQ1 : aQ0;
      #pragma unroll
      for (int n=0;n<4;n++) {
        const int rowA = n*16 + fr;
        bf16x8 aK = *(const bf16x8*)(bKb + rowA*128 + ((kb*64 + fg*16) ^ ((rowA&7)<<4)));
        sacc[n] = __builtin_amdgcn_mfma_f32_16x16x32_bf16(aK, q, sacc[n], 0, 0, 0);
      }
    }
    __builtin_amdgcn_s_setprio(0);

    // per-lane online softmax for q=qg over its 16 kv values
    const bool diag = (kt == qt);
    float pv[16];
    #pragma unroll
    for (int n=0;n<4;n++)
      #pragma unroll
      for (int r=0;r<4;r++) {
        float xx = sacc[n][r] * 0.125f;
        if (diag) {
          const int kvg = kt*64 + n*16 + fg*4 + r;
          if (kvg > qg) xx = -INFINITY;
        }
        pv[n*4+r] = xx;
      }
    float m8[8];
    #pragma unroll
    for (int i=0;i<8;i++) m8[i] = fmaxf(pv[i], pv[i+8]);
    #pragma unroll
    for (int i=0;i<4;i++) m8[i] = fmaxf(m8[i], m8[i+4]);
    float rmax = fmaxf(fmaxf(m8[0],m8[1]), fmaxf(m8[2],m8[3]));
    rmax = fmaxf(rmax, __shfl_xor(rmax, 16));
    rmax = fmaxf(rmax, __shfl_xor(rmax, 32));
    const float mnew = fmaxf(mrow, rmax);
    const float scale = __expf(mrow - mnew);
    mrow = mnew;
    float ps[16];
    #pragma unroll
    for (int i=0;i<16;i++) ps[i] = __expf(pv[i] - mnew);
    #pragma unroll
    for (int n=0;n<4;n++) {
      bf16x4 pk;
      #pragma unroll
      for (int r=0;r<4;r++) pk[r] = (bf16)ps[n*4+r];
      *(bf16x4*)(sPw + fr*128 + ((n*32 + fg*8) ^ swzP)) = pk;
    }
    float s8[8];
    #pragma unroll
    for (int i=0;i<8;i++) s8[i] = ps[i] + ps[i+8];
    #pragma unroll
    for (int i=0;i<4;i++) s8[i] += s8[i+4];
    float rsum = (s8[0]+s8[1]) + (s8[2]+s8[3]);
    rsum += __shfl_xor(rsum, 16);
    rsum += __shfl_xor(rsum, 32);
    lrow = lrow*scale + rsum;
    float sc[4];
    #pragma unroll
    for (int r=0;r<4;r++) sc[r] = __shfl(scale, fg*4 + r);
    #pragma unroll
    for (int n=0;n<4;n++)
      #pragma unroll
      for (int r=0;r<4;r++) o_acc[n][r] *= sc[r];
    asm volatile("s_waitcnt lgkmcnt(0)" ::: "memory");  // P visible wave-wide

    // O += P V
    bf16x8 aP0 = *(const bf16x8*)(sPw + fr*128 + ((fg*16) ^ swzP));
    bf16x8 aP1 = *(const bf16x8*)(sPw + fr*128 + ((64 + fg*16) ^ swzP));
    __builtin_amdgcn_s_setprio(1);
    #pragma unroll
    for (int n=0;n<4;n++) {
      const int rowV = n*16 + fr;
      bf16x8 bV0 = *(const bf16x8*)(bVb + rowV*128 + ((fg*16) ^ ((rowV&7)<<4)));
      bf16x8 bV1 = *(const bf16x8*)(bVb + rowV*128 + ((64 + fg*16) ^ ((rowV&7)<<4)));
      o_acc[n] = __builtin_amdgcn_mfma_f32_16x16x32_bf16(aP0, bV0, o_acc[n], 0, 0, 0);
      o_acc[n] = __builtin_amdgcn_mfma_f32_16x16x32_bf16(aP1, bV1, o_acc[n], 0, 0, 0);
    }
    __builtin_amdgcn_s_setprio(0);
  }

  const float linv = 1.0f / lrow;
  float inv4[4];
  #pragma unroll
  for (int r=0;r<4;r++) inv4[r] = __shfl(linv, fg*4 + r);
  #pragma unroll
  for (int r=0;r<4;r++) {
    const int qq = q0 + wid*16 + fg*4 + r;
    #pragma unroll
    for (int n=0;n<4;n++) {
      O[((size_t)b*MM + qq)*DD + h*HD + n*16 + fr] = (bf16)(o_acc[n][r] * inv4[r]);
    }
  }
}

// ---------------- GEMM 3: out = O @ out_w^T + out_b (fp32 out) ------------
__global__ __launch_bounds__(256) void k_gemm_out(
    const bf16* __restrict__ A, const bf16* __restrict__ OW,
    const float* __restrict__ OBIAS, float* __restrict__ outp)
{
  __shared__ bf16 sA[3*128*32];
  __shared__ bf16 sB[3*128*32];
  const int row0 = blockIdx.x * 128;
  const int col0 = blockIdx.y * 128;
  f32x4 acc[4][4];
  gemm_core128(A, OW, row0, col0, sA, sB, acc);
  const int lane = threadIdx.x & 63, wid = threadIdx.x >> 6;
  const int wr = wid >> 1, wc = wid & 1;
  const int fr = lane & 15, fg = lane >> 4;
  #pragma unroll
  for (int n=0;n<4;n++) {
    const int gc = col0 + wc*64 + n*16 + fr;
    const float bs = OBIAS[gc];
    #pragma unroll
    for (int m=0;m<4;m++) {
      #pragma unroll
      for (int r=0;r<4;r++) {
        const int gr = row0 + wr*64 + m*16 + fg*4 + r;
        outp[(size_t)gr * DD + gc] = acc[m][n][r] + bs;
      }
    }
  }
}

// ---------------- host launcher -------------------------------------------
extern "C" void kernel_launch(void* const* d_in, const int* in_sizes, int n_in,
                              void* d_out, int out_size, void* d_ws, size_t ws_size,
                              hipStream_t stream)
{
  (void)in_sizes; (void)n_in; (void)out_size; (void)ws_size;
  const float* x   = (const float*)d_in[0];
  const float* wq  = (const float*)d_in[1];
  const float* wk  = (const float*)d_in[2];
  const float* wv  = (const float*)d_in[3];
  const float* ipw = (const float*)d_in[4];
  const float* ipb = (const float*)d_in[5];
  const float* ow  = (const float*)d_in[6];
  const float* ob  = (const float*)d_in[7];
  float* outp = (float*)d_out;

  char* ws = (char*)d_ws;
  const size_t MB = 1u << 20;
  bf16* xb   = (bf16*)(ws + 0*MB);    // 8 MB  (4096x1024)
  bf16* wqb  = (bf16*)(ws + 8*MB);    // 2 MB
  bf16* wkb  = (bf16*)(ws + 10*MB);   // 2 MB
  bf16* wvb  = (bf16*)(ws + 12*MB);   // 2 MB
  bf16* ipwb = (bf16*)(ws + 14*MB);   // 6 MB  (3072x1024)
  bf16* owb  = (bf16*)(ws + 20*MB);   // 2 MB
  bf16* QKV  = (bf16*)(ws + 22*MB);   // 24 MB (3 x 4096x1024)
  bf16* QH   = (bf16*)(ws + 46*MB);   // 8 MB
  bf16* KH   = (bf16*)(ws + 54*MB);   // 8 MB
  bf16* VT   = (bf16*)(ws + 62*MB);   // 8 MB  (2 x 1024 x 2048, transposed)
  bf16* Ob   = (bf16*)(ws + 70*MB);   // 8 MB

  k_cvt_all<<<11264, 256, 0, stream>>>(x, wq, wk, wv, ipw, ow,
                                       xb, wqb, wkb, wvb, ipwb, owb);
  k_rope256<<<dim3(16,4,3), 512, 0, stream>>>(xb, wqb, wkb, wvb, QKV);
  k_proj256<<<dim3(16,4,3), 512, 0, stream>>>(QKV, ipwb, ipb, QH, KH, VT);
  k_attn<<<dim3(32,16,2), 256, 0, stream>>>(QH, KH, VT, Ob);
  k_gemm_out<<<dim3(32,8,1), 256, 0, stream>>>(Ob, owb, ob, outp);
}

// Round 7
// 154.362 us; speedup vs baseline: 1.3459x; 1.3459x over previous
//
#include <hip/hip_runtime.h>
#include <hip/hip_bf16.h>
#include <math.h>

typedef __bf16 bf16;
typedef __bf16 bf16x4 __attribute__((ext_vector_type(4)));
typedef __bf16 bf16x8 __attribute__((ext_vector_type(8)));
typedef float  f32x4  __attribute__((ext_vector_type(4)));

#define MM 2048   // seq len
#define DD 1024   // model dim
#define HD 64     // head dim

// async global->LDS, 16B per lane. LDS dest must be wave-uniform base + lane*16.
__device__ __forceinline__ void gload16(const void* g, void* l) {
  __builtin_amdgcn_global_load_lds((const __attribute__((address_space(1))) void*)g,
                                   (__attribute__((address_space(3))) void*)l, 16, 0, 0);
}

// ---------------- fp32 -> bf16 conversion (all tensors, one launch) -------
__global__ __launch_bounds__(256) void k_cvt_all(
    const float* __restrict__ x,   const float* __restrict__ wq,
    const float* __restrict__ wk,  const float* __restrict__ wv,
    const float* __restrict__ ipw, const float* __restrict__ ow,
    bf16* __restrict__ xb,  bf16* __restrict__ wqb, bf16* __restrict__ wkb,
    bf16* __restrict__ wvb, bf16* __restrict__ ipwb, bf16* __restrict__ owb)
{
  int bid = blockIdx.x;
  const float* s; bf16* d; int base;
  if (bid < 4096)       { s = x;   d = xb;   base = bid; }
  else if (bid < 5120)  { s = wq;  d = wqb;  base = bid - 4096; }
  else if (bid < 6144)  { s = wk;  d = wkb;  base = bid - 5120; }
  else if (bid < 7168)  { s = wv;  d = wvb;  base = bid - 6144; }
  else if (bid < 10240) { s = ipw; d = ipwb; base = bid - 7168; }
  else                  { s = ow;  d = owb;  base = bid - 10240; }
  int i = base*256 + threadIdx.x;          // float4 index
  float4 v = ((const float4*)s)[i];
  bf16x4 o;
  o[0]=(bf16)v.x; o[1]=(bf16)v.y; o[2]=(bf16)v.z; o[3]=(bf16)v.w;
  ((bf16x4*)d)[i] = o;
}

// ---------------- shared GEMM core: C(128x128) = A(MxK) * B(NxK)^T --------
// 256 threads = 4 waves (2x2), wave does 64x64 out (4x4 16x16x32 frags).
// BK=64: 2 LDS buffers x (A 16KB + B 16KB) = 64KB -> 2 blocks/CU.
// Per K-tile: barrier; issue 8 gload16 for kt+1; vmcnt(8) [counted, never 0
// mid-loop]; barrier; 16 ds_read_b128; 32 MFMA. Halves sync ops vs BK=32.
// LDS layout: [buf][128 rows][8 chunks of 16B], phys chunk = (logical +
// (row&7)) & 7 -- 8-chunk rotation, conflict-free frag reads (r4-verified
// structure: 8 bank-spans x 8 lanes). Rotation folded into GLOBAL source.
__device__ __forceinline__ void gemm_core(const bf16* __restrict__ A,
                                          const bf16* __restrict__ Bw,
                                          const int row0, const int col0,
                                          bf16* __restrict__ sA, bf16* __restrict__ sB,
                                          f32x4 (&acc)[4][4])
{
  const int t = threadIdx.x;
  #pragma unroll
  for (int m=0;m<4;m++)
    #pragma unroll
    for (int n=0;n<4;n++)
      acc[m][n] = (f32x4){0.f,0.f,0.f,0.f};

  // staging: issue jj covers rows jj*32..+31; thread t -> row jj*32+(t>>3),
  // phys chunk t&7, logical chunk ((t&7)-(row&7))&7 folded into source col.
  const int srow = t >> 3;                        // 0..31
  const int lch  = ((t & 7) - (srow & 7)) & 7;
  const bf16* gA = A  + (size_t)(row0 + srow)*DD + lch*8;
  const bf16* gB = Bw + (size_t)(col0 + srow)*DD + lch*8;
  char* lA = (char*)sA + t*16;
  char* lB = (char*)sB + t*16;

  const int lane = t & 63, wid = t >> 6;
  const int wr = wid >> 1, wc = wid & 1;
  const int fr = lane & 15, fg = lane >> 4;
  const int fr7 = fr & 7;

  // prologue: stage kt=0 into buffer 0
  #pragma unroll
  for (int jj=0;jj<4;jj++) gload16(gA + (size_t)jj*32*DD, lA + jj*4096);
  #pragma unroll
  for (int jj=0;jj<4;jj++) gload16(gB + (size_t)jj*32*DD, lB + jj*4096);

  for (int kt = 0; kt < 16; ++kt) {
    const int buf = kt & 1;
    __builtin_amdgcn_s_barrier();        // all waves done reading buf^1 (kt-1)
    if (kt < 15) {
      const int nb = buf ^ 1;
      const int ko = (kt + 1) * 64;
      #pragma unroll
      for (int jj=0;jj<4;jj++) gload16(gA + (size_t)jj*32*DD + ko, lA + nb*16384 + jj*4096);
      #pragma unroll
      for (int jj=0;jj<4;jj++) gload16(gB + (size_t)jj*32*DD + ko, lB + nb*16384 + jj*4096);
      asm volatile("s_waitcnt vmcnt(8)" ::: "memory");   // kt's 8 done; kt+1's in flight
    } else {
      asm volatile("s_waitcnt vmcnt(0)" ::: "memory");
    }
    __builtin_amdgcn_s_barrier();        // all waves' kt DMA drained
    const char* bA = (const char*)sA + buf*16384;
    const char* bB = (const char*)sB + buf*16384;
    bf16x8 aF[2][4], bF[2][4];
    #pragma unroll
    for (int kb=0;kb<2;kb++) {
      #pragma unroll
      for (int m=0;m<4;m++)
        aF[kb][m] = *(const bf16x8*)(bA + (wr*64 + m*16 + fr)*128 + ((kb*4 + fg + fr7)&7)*16);
      #pragma unroll
      for (int n=0;n<4;n++)
        bF[kb][n] = *(const bf16x8*)(bB + (wc*64 + n*16 + fr)*128 + ((kb*4 + fg + fr7)&7)*16);
    }
    __builtin_amdgcn_s_setprio(1);
    #pragma unroll
    for (int kb=0;kb<2;kb++)
      #pragma unroll
      for (int m=0;m<4;m++)
        #pragma unroll
        for (int n=0;n<4;n++)
          acc[m][n] = __builtin_amdgcn_mfma_f32_16x16x32_bf16(aF[kb][m], bF[kb][n], acc[m][n], 0, 0, 0);
    __builtin_amdgcn_s_setprio(0);
  }
}

// ---------------- GEMM 1: q/k/v = rope(x @ W^T), z picks W ----------------
__global__ __launch_bounds__(256, 2) void k_gemm_rope(
    const bf16* __restrict__ X, const bf16* __restrict__ Wq,
    const bf16* __restrict__ Wk, const bf16* __restrict__ Wv,
    bf16* __restrict__ QKV)
{
  __shared__ bf16 sA[2*128*64];   // 32 KB
  __shared__ bf16 sB[2*128*64];   // 32 KB
  const int row0 = blockIdx.x * 128;
  const int col0 = blockIdx.y * 128;
  const int z = blockIdx.z;
  const bf16* Bw = (z==0) ? Wq : ((z==1) ? Wk : Wv);
  f32x4 acc[4][4];
  gemm_core(X, Bw, row0, col0, sA, sB, acc);

  bf16* outp = QKV + (size_t)z * (4096u*1024u);
  const int lane = threadIdx.x & 63, wid = threadIdx.x >> 6;
  const int wr = wid >> 1, wc = wid & 1;
  const int fr = lane & 15, fg = lane >> 4;
  #pragma unroll
  for (int n=0;n<4;n++) {
    const int gc = col0 + wc*64 + n*16 + fr;
    const int i2 = gc >> 1;
    // theta = 10000^(-2*(i-1)/1024) = exp((i-1) * (-2*ln(1e4)/1024))
    const float theta = __expf(((float)i2 - 1.0f) * (-2.0f * 9.210340371976184f / 1024.0f));
    #pragma unroll
    for (int m=0;m<4;m++) {
      #pragma unroll
      for (int r=0;r<4;r++) {
        const int gr = row0 + wr*64 + m*16 + fg*4 + r;
        const float v  = acc[m][n][r];
        const float pv = __shfl_xor(v, 1);      // partner column of the pair
        const int pos = gr & (MM-1);
        float sv, cv;
        __sincosf((float)pos * theta, &sv, &cv);
        const float res = (gc & 1) ? (v*cv - pv*sv) : (v*cv + pv*sv);
        outp[(size_t)gr * DD + gc] = (bf16)res;
      }
    }
  }
}

// ------- GEMM 2: qh/kh = q/k @ Wi^T + b (bf16), vh stored TRANSPOSED ------
// QH is pre-scaled by 0.125 (= 1/sqrt(64)) so attention skips the score scale.
__global__ __launch_bounds__(256, 2) void k_gemm_proj(
    const bf16* __restrict__ QKV, const bf16* __restrict__ IPW,
    const float* __restrict__ IPB,
    bf16* __restrict__ QH, bf16* __restrict__ KH, bf16* __restrict__ VT)
{
  __shared__ bf16 sA[2*128*64];
  __shared__ bf16 sB[2*128*64];
  const int row0 = blockIdx.x * 128;
  const int col0 = blockIdx.y * 128;
  const int z = blockIdx.z;
  const bf16* A  = QKV + (size_t)z * (4096u*1024u);
  const bf16* Bw = IPW + (size_t)z * (1024u*1024u);
  const float* bias = IPB + z * DD;
  f32x4 acc[4][4];
  gemm_core(A, Bw, row0, col0, sA, sB, acc);

  const int lane = threadIdx.x & 63, wid = threadIdx.x >> 6;
  const int wr = wid >> 1, wc = wid & 1;
  const int fr = lane & 15, fg = lane >> 4;
  if (z < 2) {
    bf16* outp = (z==0) ? QH : KH;
    const float vscale = (z==0) ? 0.125f : 1.0f;
    #pragma unroll
    for (int n=0;n<4;n++) {
      const int gc = col0 + wc*64 + n*16 + fr;
      const float bs = bias[gc];
      #pragma unroll
      for (int m=0;m<4;m++) {
        #pragma unroll
        for (int r=0;r<4;r++) {
          const int gr = row0 + wr*64 + m*16 + fg*4 + r;
          outp[(size_t)gr * DD + gc] = (bf16)((acc[m][n][r] + bs) * vscale);
        }
      }
    }
  } else {
    // VT layout: (B, D, M) so attention PV B-frags read contiguous along m
    #pragma unroll
    for (int n=0;n<4;n++) {
      const int gc = col0 + wc*64 + n*16 + fr;
      const float bs = bias[gc];
      #pragma unroll
      for (int m=0;m<4;m++) {
        const int gr0 = row0 + wr*64 + m*16 + fg*4;   // 4 consecutive rows
        const int b  = gr0 >> 11;
        const int m0 = gr0 & (MM-1);
        bf16x4 pk;
        #pragma unroll
        for (int r=0;r<4;r++) pk[r] = (bf16)(acc[m][n][r] + bs);
        *(bf16x4*)(VT + ((size_t)b*DD + gc)*MM + m0) = pk;
      }
    }
  }
}

// ---------------- flash attention (causal) --------------------------------
// 512 uniform blocks (paired q-tiles: 33 KV tiles each), XCD-grouped so each
// XCD serves only 4 (h,b) combos -> 2MB KV, L2-resident. 3-buffer depth-2
// K/V pipeline (global_load_lds, pre-swizzled source), ONE raw barrier +
// counted vmcnt(4) per tile. Swapped QK^T: softmax lane-local. Q pre-scaled.
// Defer-max (THR=8) skips the O-rescale on most tiles.
__global__ __launch_bounds__(256) void k_attn(
    const bf16* __restrict__ QH, const bf16* __restrict__ KH,
    const bf16* __restrict__ VT, bf16* __restrict__ O)
{
  __shared__ bf16 sK[3*64*64];    // [buf][kv][d] rows of 128B, swizzled
  __shared__ bf16 sV[3*64*64];    // [buf][d][kv] (from VT), swizzled
  __shared__ bf16 sP[4*16*64];    // per-wave P tile [16 q][64 kv] swizzled
  // XCD-grouped decode: idx&7 = XCD slot; 4 (h,b) combos per XCD.
  const int idx = blockIdx.x;
  const int xcd = idx & 7;
  const int rr  = idx >> 3;                  // 0..63
  const int combo = xcd*4 + (rr & 3);        // 0..31
  const int b = combo >> 4, h = combo & 15;
  const int pair = rr >> 2;                  // 0..15
  const int t = threadIdx.x, lane = t & 63, wid = t >> 6;
  const int fr = lane & 15, fg = lane >> 4;
  const int swzP = (fr & 7) << 4;

  // staging geometry (pre-swizzled global source, linear LDS dest t*16)
  const int srow = t >> 3;                       // 0..31
  const int cc   = (t & 7) ^ (srow & 7);
  const bf16* gK0 = KH + ((size_t)b*MM + srow)*DD + h*HD + cc*8;
  const bf16* gK1 = gK0 + (size_t)32*DD;
  const bf16* gV0 = VT + ((size_t)b*DD + h*HD + srow)*MM + cc*8;
  const bf16* gV1 = gV0 + (size_t)32*MM;
  char* lK = (char*)sK + t*16;
  char* lV = (char*)sV + t*16;
  char* sPw = (char*)(sP + wid*16*64);

  #pragma unroll 1
  for (int half = 0; half < 2; ++half) {
    const int qt = half ? pair : (31 - pair);
    const int q0 = qt * 64;
    const int qg = q0 + wid*16 + fr;           // this lane's q row (softmax)

    const bf16* qp = QH + ((size_t)b*MM + qg)*DD + h*HD + fg*8;
    bf16x8 aQ0 = *(const bf16x8*)qp;
    bf16x8 aQ1 = *(const bf16x8*)(qp + 32);

    if (half) __builtin_amdgcn_s_barrier();    // close half-0 LDS reads

    // stage tiles 0 (,1)
    gload16(gK0, lK);  gload16(gK1, lK + 4096);
    gload16(gV0, lV);  gload16(gV1, lV + 4096);
    if (qt >= 1) {
      gload16(gK0 + (size_t)64*DD, lK + 8192);
      gload16(gK1 + (size_t)64*DD, lK + 8192 + 4096);
      gload16(gV0 + 64, lV + 8192);
      gload16(gV1 + 64, lV + 8192 + 4096);
    }

    f32x4 o_acc[4];
    #pragma unroll
    for (int n=0;n<4;n++) o_acc[n] = (f32x4){0.f,0.f,0.f,0.f};
    float mrow = -INFINITY, lrow = 0.f;

    int c = 0;
    for (int kt = 0; kt <= qt; ++kt) {
      if (kt < qt) asm volatile("s_waitcnt vmcnt(4)" ::: "memory");
      else         asm volatile("s_waitcnt vmcnt(0)" ::: "memory");
      __builtin_amdgcn_s_barrier();            // all waves' tile-kt DMA done
      if (kt + 2 <= qt) {
        const int nb = (c + 2 < 3) ? c + 2 : c - 1;
        gload16(gK0 + (size_t)(kt+2)*64*DD, lK + nb*8192);
        gload16(gK1 + (size_t)(kt+2)*64*DD, lK + nb*8192 + 4096);
        gload16(gV0 + (kt+2)*64,            lV + nb*8192);
        gload16(gV1 + (kt+2)*64,            lV + nb*8192 + 4096);
      }
      const char* bKb = (const char*)sK + c*8192;
      const char* bVb = (const char*)sV + c*8192;

      // S^T = K Q^T : lane holds S[kv=n*16+fg*4+r][q=fr]
      f32x4 sacc[4];
      #pragma unroll
      for (int n=0;n<4;n++) sacc[n] = (f32x4){0.f,0.f,0.f,0.f};
      __builtin_amdgcn_s_setprio(1);
      #pragma unroll
      for (int kb=0;kb<2;kb++) {
        const bf16x8 q = kb ? aQ1 : aQ0;
        #pragma unroll
        for (int n=0;n<4;n++) {
          const int rowA = n*16 + fr;
          bf16x8 aK = *(const bf16x8*)(bKb + rowA*128 + ((kb*64 + fg*16) ^ ((rowA&7)<<4)));
          sacc[n] = __builtin_amdgcn_mfma_f32_16x16x32_bf16(aK, q, sacc[n], 0, 0, 0);
        }
      }
      __builtin_amdgcn_s_setprio(0);

      // per-lane online softmax for q=qg over its 16 kv values (Q pre-scaled)
      const bool diag = (kt == qt);
      float pv[16];
      #pragma unroll
      for (int n=0;n<4;n++)
        #pragma unroll
        for (int r=0;r<4;r++) {
          float xx = sacc[n][r];
          if (diag) {
            const int kvg = kt*64 + n*16 + fg*4 + r;
            if (kvg > qg) xx = -INFINITY;
          }
          pv[n*4+r] = xx;
        }
      float m8[8];
      #pragma unroll
      for (int i=0;i<8;i++) m8[i] = fmaxf(pv[i], pv[i+8]);
      #pragma unroll
      for (int i=0;i<4;i++) m8[i] = fmaxf(m8[i], m8[i+4]);
      float rmax = fmaxf(fmaxf(m8[0],m8[1]), fmaxf(m8[2],m8[3]));
      rmax = fmaxf(rmax, __shfl_xor(rmax, 16));
      rmax = fmaxf(rmax, __shfl_xor(rmax, 32));
      // defer-max: only rescale when the running max grew by > 8
      if (!__all(rmax - mrow <= 8.f)) {
        const float mnew = fmaxf(mrow, rmax);
        const float scale = __expf(mrow - mnew);
        mrow = mnew;
        lrow *= scale;
        float sc[4];
        #pragma unroll
        for (int r=0;r<4;r++) sc[r] = __shfl(scale, fg*4 + r);
        #pragma unroll
        for (int n=0;n<4;n++)
          #pragma unroll
          for (int r=0;r<4;r++) o_acc[n][r] *= sc[r];
      }
      float ps[16];
      #pragma unroll
      for (int i=0;i<16;i++) ps[i] = __expf(pv[i] - mrow);
      #pragma unroll
      for (int n=0;n<4;n++) {
        bf16x4 pk;
        #pragma unroll
        for (int r=0;r<4;r++) pk[r] = (bf16)ps[n*4+r];
        *(bf16x4*)(sPw + fr*128 + ((n*32 + fg*8) ^ swzP)) = pk;
      }
      float s8[8];
      #pragma unroll
      for (int i=0;i<8;i++) s8[i] = ps[i] + ps[i+8];
      #pragma unroll
      for (int i=0;i<4;i++) s8[i] += s8[i+4];
      float rsum = (s8[0]+s8[1]) + (s8[2]+s8[3]);
      rsum += __shfl_xor(rsum, 16);
      rsum += __shfl_xor(rsum, 32);
      lrow += rsum;
      asm volatile("s_waitcnt lgkmcnt(0)" ::: "memory");  // P visible wave-wide

      // O += P V
      bf16x8 aP0 = *(const bf16x8*)(sPw + fr*128 + ((fg*16) ^ swzP));
      bf16x8 aP1 = *(const bf16x8*)(sPw + fr*128 + ((64 + fg*16) ^ swzP));
      __builtin_amdgcn_s_setprio(1);
      #pragma unroll
      for (int n=0;n<4;n++) {
        const int rowV = n*16 + fr;
        bf16x8 bV0 = *(const bf16x8*)(bVb + rowV*128 + ((fg*16) ^ ((rowV&7)<<4)));
        bf16x8 bV1 = *(const bf16x8*)(bVb + rowV*128 + ((64 + fg*16) ^ ((rowV&7)<<4)));
        o_acc[n] = __builtin_amdgcn_mfma_f32_16x16x32_bf16(aP0, bV0, o_acc[n], 0, 0, 0);
        o_acc[n] = __builtin_amdgcn_mfma_f32_16x16x32_bf16(aP1, bV1, o_acc[n], 0, 0, 0);
      }
      __builtin_amdgcn_s_setprio(0);
      c = (c == 2) ? 0 : c + 1;
    }

    // epilogue: normalize (inv for q=fg*4+r from lane fg*4+r) and store
    const float linv = 1.0f / lrow;
    float inv4[4];
    #pragma unroll
    for (int r=0;r<4;r++) inv4[r] = __shfl(linv, fg*4 + r);
    #pragma unroll
    for (int r=0;r<4;r++) {
      const int qq = q0 + wid*16 + fg*4 + r;
      #pragma unroll
      for (int n=0;n<4;n++) {
        O[((size_t)b*MM + qq)*DD + h*HD + n*16 + fr] = (bf16)(o_acc[n][r] * inv4[r]);
      }
    }
  }
}

// ---------------- GEMM 3: out = O @ out_w^T + out_b (fp32 out) ------------
__global__ __launch_bounds__(256, 2) void k_gemm_out(
    const bf16* __restrict__ A, const bf16* __restrict__ OW,
    const float* __restrict__ OBIAS, float* __restrict__ outp)
{
  __shared__ bf16 sA[2*128*64];
  __shared__ bf16 sB[2*128*64];
  const int row0 = blockIdx.x * 128;
  const int col0 = blockIdx.y * 128;
  f32x4 acc[4][4];
  gemm_core(A, OW, row0, col0, sA, sB, acc);
  const int lane = threadIdx.x & 63, wid = threadIdx.x >> 6;
  const int wr = wid >> 1, wc = wid & 1;
  const int fr = lane & 15, fg = lane >> 4;
  #pragma unroll
  for (int n=0;n<4;n++) {
    const int gc = col0 + wc*64 + n*16 + fr;
    const float bs = OBIAS[gc];
    #pragma unroll
    for (int m=0;m<4;m++) {
      #pragma unroll
      for (int r=0;r<4;r++) {
        const int gr = row0 + wr*64 + m*16 + fg*4 + r;
        outp[(size_t)gr * DD + gc] = acc[m][n][r] + bs;
      }
    }
  }
}

// ---------------- host launcher -------------------------------------------
extern "C" void kernel_launch(void* const* d_in, const int* in_sizes, int n_in,
                              void* d_out, int out_size, void* d_ws, size_t ws_size,
                              hipStream_t stream)
{
  (void)in_sizes; (void)n_in; (void)out_size; (void)ws_size;
  const float* x   = (const float*)d_in[0];
  const float* wq  = (const float*)d_in[1];
  const float* wk  = (const float*)d_in[2];
  const float* wv  = (const float*)d_in[3];
  const float* ipw = (const float*)d_in[4];
  const float* ipb = (const float*)d_in[5];
  const float* ow  = (const float*)d_in[6];
  const float* ob  = (const float*)d_in[7];
  float* outp = (float*)d_out;

  char* ws = (char*)d_ws;
  const size_t MB = 1u << 20;
  bf16* xb   = (bf16*)(ws + 0*MB);    // 8 MB  (4096x1024)
  bf16* wqb  = (bf16*)(ws + 8*MB);    // 2 MB
  bf16* wkb  = (bf16*)(ws + 10*MB);   // 2 MB
  bf16* wvb  = (bf16*)(ws + 12*MB);   // 2 MB
  bf16* ipwb = (bf16*)(ws + 14*MB);   // 6 MB  (3072x1024)
  bf16* owb  = (bf16*)(ws + 20*MB);   // 2 MB
  bf16* QKV  = (bf16*)(ws + 22*MB);   // 24 MB (3 x 4096x1024)
  bf16* QH   = (bf16*)(ws + 46*MB);   // 8 MB  (pre-scaled by 0.125)
  bf16* KH   = (bf16*)(ws + 54*MB);   // 8 MB
  bf16* VT   = (bf16*)(ws + 62*MB);   // 8 MB  (2 x 1024 x 2048, transposed)
  bf16* Ob   = (bf16*)(ws + 70*MB);   // 8 MB

  k_cvt_all<<<11264, 256, 0, stream>>>(x, wq, wk, wv, ipw, ow,
                                       xb, wqb, wkb, wvb, ipwb, owb);
  k_gemm_rope<<<dim3(32,8,3), 256, 0, stream>>>(xb, wqb, wkb, wvb, QKV);
  k_gemm_proj<<<dim3(32,8,3), 256, 0, stream>>>(QKV, ipwb, ipb, QH, KH, VT);
  k_attn<<<512, 256, 0, stream>>>(QH, KH, VT, Ob);
  k_gemm_out<<<dim3(32,8,1), 256, 0, stream>>>(Ob, owb, ob, outp);
}